// Round 12
// baseline (237.476 us; speedup 1.0000x reference)
//
#include <hip/hip_runtime.h>
#include <hip/hip_bf16.h>
#include <math.h>

// ---------------------------------------------------------------------------
// SemlaSelfAttention — MI355X (gfx950)
// Round 12 = round 10 structure (best: gemm 134us, traffic 49+141 MB) with
//            the gemm re-partitioned across 8 waves/block (512 thr, M=64):
//            acc per wave halves (32+24 AGPR), __launch_bounds__(512,6)
//            caps VGPR -> 3 blocks/CU = 24 waves/CU (75%) vs 16 (40%).
//            Same grid, same per-block memory footprint -> traffic unchanged;
//            isolates OCCUPANCY as the variable. einsum/proj/preps identical.
// ---------------------------------------------------------------------------

typedef __attribute__((ext_vector_type(8))) short short8;
typedef __attribute__((ext_vector_type(8))) __bf16 bf16x8;
typedef __attribute__((ext_vector_type(4))) float f32x4;

constexpr int EQUI_OFF = 0;          // 4*256*3*64 floats
constexpr int INV_OFF  = 196608;     // 4*256*256
constexpr int EDGE_OFF = 458752;     // 4*256*256*64

__device__ __forceinline__ unsigned short f2bf(float x) {
    unsigned u = __builtin_bit_cast(unsigned, x);
    u = u + 0x7FFFu + ((u >> 16) & 1u);   // RNE (prep kernels only)
    return (unsigned short)(u >> 16);
}
__device__ __forceinline__ float bf2f(unsigned short u) {
    return __builtin_bit_cast(float, ((unsigned)u) << 16);
}
__device__ __forceinline__ unsigned short f2bfh(float x) {   // native v_cvt (RNE)
    return __builtin_bit_cast(unsigned short, (__bf16)x);
}
__device__ __forceinline__ unsigned pk2(float a, float b) {
    return (unsigned)f2bfh(a) | ((unsigned)f2bfh(b) << 16);
}
__device__ __forceinline__ short8 pk8(f32x4 a, f32x4 b) {
    bf16x8 r = { (__bf16)a.x, (__bf16)a.y, (__bf16)a.z, (__bf16)a.w,
                 (__bf16)b.x, (__bf16)b.y, (__bf16)b.z, (__bf16)b.w };
    return __builtin_bit_cast(short8, r);
}
__device__ __forceinline__ f32x4 MFMA(short8 a, short8 b, f32x4 c) {
    return __builtin_amdgcn_mfma_f32_16x16x32_bf16(
        __builtin_bit_cast(bf16x8, a), __builtin_bit_cast(bf16x8, b), c, 0, 0, 0);
}

// ---------------------------------------------------------------------------
// prep1: projections (blocks 0..2047) + weight transposes (2048..2335)
// ---------------------------------------------------------------------------
__global__ void prep1(const float* __restrict__ invs, const float* __restrict__ equis,
                      const float* __restrict__ qW, const float* __restrict__ qb,
                      const float* __restrict__ kW, const float* __restrict__ kb,
                      const float* __restrict__ inv_inW, const float* __restrict__ inv_inb,
                      const float* __restrict__ equi_inW,
                      const float* __restrict__ mW1, const float* __restrict__ mW2,
                      float* __restrict__ qm, float* __restrict__ km,
                      float* __restrict__ hf, float* __restrict__ pe,
                      short* __restrict__ W1T, short* __restrict__ W2T) {
    int tid = threadIdx.x, bi = blockIdx.x;
    if (bi < 1024) {
        int r = bi;
        __shared__ float sInv[256];
        sInv[tid] = invs[r * 256 + tid];
        __syncthreads();
        if (tid < 64) {
            float acc = qb[tid];
            for (int f = 0; f < 256; ++f) acc += sInv[f] * qW[f * 64 + tid];
            qm[r * 64 + tid] = acc;
        } else if (tid < 128) {
            int c = tid - 64;
            float acc = kb[c];
            for (int f = 0; f < 256; ++f) acc += sInv[f] * kW[f * 64 + c];
            km[r * 64 + c] = acc;
        }
        float acch = inv_inb[tid];
        for (int f = 0; f < 256; ++f) acch += sInv[f] * inv_inW[f * 256 + tid];
        hf[r * 256 + tid] = acch;
    } else if (bi < 2048) {
        int rn = bi - 1024;
        if (tid < 192) {
            int d = tid >> 6, c = tid & 63;
            const float* erow = equis + (size_t)rn * 192 + d * 64;
            float acc = 0.f;
            for (int f = 0; f < 64; ++f) acc += erow[f] * equi_inW[f * 64 + c];
            pe[rn * 192 + d * 64 + c] = acc;
        }
    } else {
        int idx = (bi - 2048) * 256 + tid;          // 288 blocks -> 73728 elems
        if (idx < 32768) {                          // W1T[n][kk] = mW1[128+kk][n]
            int n = idx >> 7, kk = idx & 127;
            W1T[idx] = (short)f2bf(mW1[(128 + kk) * 256 + n]);
        } else {                                    // W2T[n][f] = mW2[f][n]
            int i2 = idx - 32768;
            int n = i2 >> 8, f = i2 & 255;
            W2T[i2] = (short)f2bf(mW2[f * 160 + n]);
        }
    }
}

// ---------------------------------------------------------------------------
// prep2: c1/c2 folds (blocks 0..2047) + bf16 transposes (2048..2192)
// ---------------------------------------------------------------------------
__global__ void prep2(const float* __restrict__ qm, const float* __restrict__ km,
                      const float* __restrict__ mW1, const float* __restrict__ mb1,
                      const float* __restrict__ hf, const float* __restrict__ pe,
                      const float* __restrict__ inv_outW, const float* __restrict__ equi_outW,
                      float* __restrict__ c1, float* __restrict__ c2,
                      unsigned short* __restrict__ hfT, unsigned short* __restrict__ peT,
                      unsigned short* __restrict__ WoT, unsigned short* __restrict__ EoT) {
    __shared__ float sT[64][65];
    int tid = threadIdx.x, bi = blockIdx.x;
    if (bi < 1024) {
        int r = bi;
        if (tid < 64) sT[0][tid] = qm[r * 64 + tid];
        __syncthreads();
        float acc = mb1[tid];
        #pragma unroll 8
        for (int k = 0; k < 64; ++k) acc = fmaf(sT[0][k], mW1[k * 256 + tid], acc);
        c1[r * 256 + tid] = acc;
    } else if (bi < 2048) {
        int r = bi - 1024;
        if (tid < 64) sT[0][tid] = km[r * 64 + tid];
        __syncthreads();
        float acc = 0.f;
        #pragma unroll 8
        for (int k = 0; k < 64; ++k) acc = fmaf(sT[0][k], mW1[(64 + k) * 256 + tid], acc);
        c2[r * 256 + tid] = acc;
    } else {
        int bt = bi - 2048;
        if (bt < 64) {            // hfT[b][hd][j] = hf[b,j,hd]
            int b = bt >> 4, t = bt & 15, tj = t >> 2, th = t & 3;
            #pragma unroll
            for (int i = 0; i < 16; ++i) { int idx = i * 256 + tid; int jl = idx >> 6, hl = idx & 63;
                sT[jl][hl] = hf[((size_t)(b * 256 + tj * 64 + jl)) * 256 + th * 64 + hl]; }
            __syncthreads();
            #pragma unroll
            for (int i = 0; i < 16; ++i) { int idx = i * 256 + tid; int hl = idx >> 6, jl = idx & 63;
                hfT[((size_t)(b * 256 + th * 64 + hl)) * 256 + tj * 64 + jl] = f2bf(sT[jl][hl]); }
        } else if (bt < 128) {    // peT[b][c][d][j] = pe[b,j,d,c]; d=3 zeroed
            int i2 = bt - 64; int b = i2 >> 4, t = i2 & 15, tj = t >> 2, d = t & 3;
            if (d == 3) {
                #pragma unroll
                for (int i = 0; i < 16; ++i) { int idx = i * 256 + tid; int c = idx >> 6, jl = idx & 63;
                    peT[((size_t)((b * 64 + c) * 4 + 3)) * 256 + tj * 64 + jl] = 0; }
            } else {
                #pragma unroll
                for (int i = 0; i < 16; ++i) { int idx = i * 256 + tid; int jl = idx >> 6, c = idx & 63;
                    sT[jl][c] = pe[((size_t)(b * 256 + tj * 64 + jl)) * 192 + d * 64 + c]; }
                __syncthreads();
                #pragma unroll
                for (int i = 0; i < 16; ++i) { int idx = i * 256 + tid; int c = idx >> 6, jl = idx & 63;
                    peT[((size_t)((b * 64 + c) * 4 + d)) * 256 + tj * 64 + jl] = f2bf(sT[jl][c]); }
            }
        } else if (bt < 144) {    // WoT[n][f] = inv_outW[f][n]
            int i2 = bt - 128; int tf = i2 >> 2, tn = i2 & 3;
            #pragma unroll
            for (int i = 0; i < 16; ++i) { int idx = i * 256 + tid; int fl = idx >> 6, nl = idx & 63;
                sT[fl][nl] = inv_outW[(size_t)(tf * 64 + fl) * 256 + tn * 64 + nl]; }
            __syncthreads();
            #pragma unroll
            for (int i = 0; i < 16; ++i) { int idx = i * 256 + tid; int nl = idx >> 6, fl = idx & 63;
                WoT[(size_t)(tn * 64 + nl) * 256 + tf * 64 + fl] = f2bf(sT[fl][nl]); }
        } else {                  // EoT[c'][c] = equi_outW[c][c']
            #pragma unroll
            for (int i = 0; i < 16; ++i) { int idx = i * 256 + tid; int cl = idx >> 6, c2i = idx & 63;
                sT[cl][c2i] = equi_outW[cl * 64 + c2i]; }
            __syncthreads();
            #pragma unroll
            for (int i = 0; i < 16; ++i) { int idx = i * 256 + tid; int c2i = idx >> 6, cl = idx & 63;
                EoT[c2i * 64 + cl] = f2bf(sT[cl][c2i]); }
        }
    }
}

// ---------------------------------------------------------------------------
// GEMM kernel: one block per (b,q,jc); 8 waves (512 thr); M=64 rows
// wave (wm,wn): wm = rows half (32), wn = n-quarter.  ~34 KB LDS.
// ---------------------------------------------------------------------------
constexpr int GA_AH   = 0;        // A: 64x128 bf16 (16K) / H: 64x256 (32K) / sPT 96x136B
constexpr int GA_EQ   = 32768;    // 192 f32
constexpr int GA_MASK = 33536;    // 64 f32
constexpr int GA_BYTES = 33792;

__launch_bounds__(512, 6)
__global__ void semla_gemm(const float* __restrict__ equis, const float* __restrict__ edges,
                           const int* __restrict__ adj, const float* __restrict__ mb2,
                           const short* __restrict__ W1T, const short* __restrict__ W2T,
                           const float* __restrict__ c1, const float* __restrict__ c2,
                           float* __restrict__ out, unsigned short* __restrict__ PT) {
    extern __shared__ char smem[];
    float* sEQ   = (float*)(smem + GA_EQ);
    float* sMask = (float*)(smem + GA_MASK);

    const int tid  = threadIdx.x;
    const int lane = tid & 63;
    const int w    = tid >> 6;          // 0..7
    const int wm   = w >> 2;            // rows half (0,1)
    const int wn   = w & 3;             // n quarter
    const int bid  = blockIdx.x;        // bq*4 + jc
    const int bq   = bid >> 2;
    const int jc   = bid & 3;
    const int b    = bq >> 8;

    const int lrow = lane & 15;
    const int kgrp = (lane >> 4) << 3;
    const int drow = (lane >> 4) << 2;

    if (tid < 192) sEQ[tid] = equis[(size_t)bq * 192 + tid];
    if (tid < 64)  sMask[tid] = adj[(size_t)bq * 256 + (jc << 6) + tid] ? 0.f : -1e30f;

    float c1v[4];
    #pragma unroll
    for (int ni = 0; ni < 4; ++ni)
        c1v[ni] = c1[bq * 256 + (wn << 6) + (ni << 4) + lrow];
    const int ntiles = (wn < 2) ? 3 : 2;
    const int nbase  = (wn < 2) ? wn * 48 : 96 + (wn - 2) * 32;
    float b2v[3];
    #pragma unroll
    for (int ti = 0; ti < 3; ++ti)
        if (ti < ntiles) b2v[ti] = mb2[nbase + (ti << 4) + lrow];

    // LDS helpers (XOR-swizzled)
    auto stA16 = [&](int row, int colbyte, short8 v) {   // A [64][128] bf16
        int byte = ((row << 8) + colbyte) ^ ((row & 7) << 4);
        *(short8*)(smem + GA_AH + byte) = v;
    };
    auto ldA = [&](int row, int kb) -> short8 {
        int byte = ((row << 8) + (kb << 1)) ^ ((row & 7) << 4);
        return *(const short8*)(smem + GA_AH + byte);
    };
    auto stH = [&](int row, int col, unsigned short v) { // H [64][256] bf16
        int byte = ((row << 9) + (col << 1)) ^ ((row & 7) << 4);
        *(unsigned short*)(smem + GA_AH + byte) = v;
    };
    auto ldH = [&](int row, int kb) -> short8 {
        int byte = ((row << 9) + (kb << 1)) ^ ((row & 7) << 4);
        return *(const short8*)(smem + GA_AH + byte);
    };

    __syncthreads();   // sEQ/sMask visible

    // ---- build A: cols 0..63 = dot(q,j), 64..127 = edges (16B stores) ----
    {
        int r = tid >> 3, h = tid & 7;      // 64 rows x 8 threads/row
        const float* erow = equis + (size_t)((b << 8) + (jc << 6) + r) * 192;
        f32x4 lo = (f32x4)(0.f), hi = (f32x4)(0.f);
        #pragma unroll
        for (int d = 0; d < 3; ++d) {
            f32x4 e0 = *(const f32x4*)(erow + d * 64 + h * 8);
            f32x4 e1 = *(const f32x4*)(erow + d * 64 + h * 8 + 4);
            f32x4 q0 = *(const f32x4*)(sEQ + d * 64 + h * 8);
            f32x4 q1 = *(const f32x4*)(sEQ + d * 64 + h * 8 + 4);
            lo += e0 * q0; hi += e1 * q1;
        }
        stA16(r, h * 16, pk8(lo, hi));
        const float* ebase = edges + ((size_t)bq * 256 + (jc << 6)) * 64;
        f32x4 e0 = *(const f32x4*)(ebase + r * 64 + h * 8);
        f32x4 e1 = *(const f32x4*)(ebase + r * 64 + h * 8 + 4);
        stA16(r, 128 + h * 16, pk8(e0, e1));
    }
    __syncthreads();

    // ---- GEMM1: H = silu(A @ W1[128:] + c1 + c2), K=128, rows [wm*32..) ----
    f32x4 acc[2][4];
    #pragma unroll
    for (int mi = 0; mi < 2; ++mi)
        #pragma unroll
        for (int ni = 0; ni < 4; ++ni) acc[mi][ni] = (f32x4)(0.f);

    #pragma unroll
    for (int k0 = 0; k0 < 128; k0 += 32) {
        int kb = k0 + kgrp;
        int rb = (wm << 5) + lrow;
        short8 a0 = ldA(rb, kb), a1 = ldA(rb + 16, kb);
        #pragma unroll
        for (int ni = 0; ni < 4; ++ni) {
            short8 bf = *(const short8*)(W1T + ((wn << 6) + (ni << 4) + lrow) * 128 + kb);
            acc[0][ni] = MFMA(a0, bf, acc[0][ni]);
            acc[1][ni] = MFMA(a1, bf, acc[1][ni]);
        }
    }
    __syncthreads();   // all waves done reading A (H aliases A)

    const float* c2base = c2 + ((size_t)((b << 8) + (jc << 6)) << 8);
    #pragma unroll
    for (int mi = 0; mi < 2; ++mi)
        #pragma unroll
        for (int r = 0; r < 4; ++r) {
            int row = (wm << 5) + (mi << 4) + drow + r;
            const float* c2row = c2base + (row << 8);
            #pragma unroll
            for (int ni = 0; ni < 4; ++ni) {
                int n = (wn << 6) + (ni << 4) + lrow;
                float x = acc[mi][ni][r] + c1v[ni] + c2row[n];
                float hh = x * __builtin_amdgcn_rcpf(1.f + __expf(-x));
                stH(row, n, f2bfh(hh));
            }
        }
    __syncthreads();

    // ---- GEMM2: msgs = H @ W2 + b2 ; rows [wm*32..), n-tiles 3/3/2/2 per wn ----
    f32x4 acc2[2][3];
    #pragma unroll
    for (int mi = 0; mi < 2; ++mi)
        #pragma unroll
        for (int ti = 0; ti < 3; ++ti) acc2[mi][ti] = (f32x4)(0.f);

    #pragma unroll
    for (int k0 = 0; k0 < 256; k0 += 32) {
        int kb = k0 + kgrp;
        int rb = (wm << 5) + lrow;
        short8 a0 = ldH(rb, kb), a1 = ldH(rb + 16, kb);
        #pragma unroll
        for (int ti = 0; ti < 3; ++ti)
            if (ti < ntiles) {
                short8 bt = *(const short8*)(W2T + (nbase + (ti << 4) + lrow) * 256 + kb);
                acc2[0][ti] = MFMA(a0, bt, acc2[0][ti]);
                acc2[1][ti] = MFMA(a1, bt, acc2[1][ti]);
            }
    }
    __syncthreads();   // H fully consumed; smem[0..13056) reused as sPT[96][136B]

    if (wn < 2) {
        // attn cols: bias + mask -> bf16 -> transposed LDS tile (packed u32)
        #pragma unroll
        for (int ti = 0; ti < 3; ++ti) {
            int n = nbase + (ti << 4) + lrow;
            float bias = b2v[ti];
            #pragma unroll
            for (int mi = 0; mi < 2; ++mi) {
                int j0 = (wm << 5) + (mi << 4) + drow;
                f32x4 mv = *(const f32x4*)(sMask + j0);
                unsigned lo = pk2(acc2[mi][ti][0] + bias + mv.x,
                                  acc2[mi][ti][1] + bias + mv.y);
                unsigned hi = pk2(acc2[mi][ti][2] + bias + mv.z,
                                  acc2[mi][ti][3] + bias + mv.w);
                *(unsigned*)(smem + n * 136 + j0 * 2)     = lo;
                *(unsigned*)(smem + n * 136 + j0 * 2 + 4) = hi;
            }
        }
    } else {
        // edge cols: straight f32 to out
        #pragma unroll
        for (int mi = 0; mi < 2; ++mi)
            #pragma unroll
            for (int ti = 0; ti < 2; ++ti) {
                int n = nbase + (ti << 4) + lrow;
                #pragma unroll
                for (int r = 0; r < 4; ++r) {
                    int j = (jc << 6) + (wm << 5) + (mi << 4) + drow + r;
                    out[EDGE_OFF + ((size_t)bq * 256 + j) * 64 + (n - 96)] = acc2[mi][ti][r] + b2v[ti];
                }
            }
    }
    __syncthreads();

    // coalesced PT store: PT[bq*96+n][jc*64 .. +64] (64B per thread)
    if (tid < 192) {
        int n = tid >> 1, half = tid & 1;
        const char* src = smem + n * 136 + half * 64;
        unsigned short* dst = PT + (((size_t)bq * 96 + n) << 8) + (jc << 6) + half * 32;
        #pragma unroll
        for (int i = 0; i < 4; ++i)
            *(short8*)(dst + i * 8) = *(const short8*)(src + i * 16);
    }
}

// ---------------------------------------------------------------------------
// einsum kernel: one block per (b, c, qc); softmax in regs + 1 MFMA chain
// ---------------------------------------------------------------------------
constexpr int ES_A = 0;        // 64x256 bf16 swizzled = 32768
constexpr int ES_W = 32768;    // 64 f32
constexpr int ES_BYTES = 33024;

__launch_bounds__(256, 4)
__global__ void semla_einsum(const unsigned short* __restrict__ PT,
                             const unsigned short* __restrict__ hfT,
                             const unsigned short* __restrict__ peT,
                             unsigned short* __restrict__ OIb, unsigned short* __restrict__ OEb) {
    extern __shared__ char smem[];
    float* sW = (float*)(smem + ES_W);
    const int tid = threadIdx.x, lane = tid & 63, w = tid >> 6;
    const int bi = blockIdx.x;
    const int qc = bi & 3;
    const int t  = bi >> 2;
    const int b  = t / 96;
    const int c  = t - 96 * b;
    const int lrow = lane & 15, kgrp = (lane >> 4) << 3, drow = (lane >> 4) << 2;

    #pragma unroll
    for (int i = 0; i < 8; ++i) {
        int id = i * 256 + tid; int row = id >> 5, ck = id & 31;
        size_t src = (((size_t)((b << 8) + (qc << 6) + row) * 96 + c) << 8) + ck * 16;
        short8 v = *(const short8*)(PT + src);
        int byte = ((row << 9) + (ck << 4)) ^ ((row & 7) << 4);
        *(short8*)(smem + ES_A + byte) = v;
    }
    __syncthreads();

    {   // softmax: row r = tid>>2, 4 threads/row, 64 elems each, in registers
        int r = tid >> 2, p = tid & 3;
        float v[64];
        #pragma unroll
        for (int i = 0; i < 8; ++i) {
            int ck = p * 8 + i;
            int byte = ((r << 9) + (ck << 4)) ^ ((r & 7) << 4);
            short8 x = *(const short8*)(smem + ES_A + byte);
            #pragma unroll
            for (int e = 0; e < 8; ++e) v[i * 8 + e] = bf2f((unsigned short)x[e]);
        }
        float m = v[0];
        #pragma unroll
        for (int i = 1; i < 64; ++i) m = fmaxf(m, v[i]);
        m = fmaxf(m, __shfl_xor(m, 1)); m = fmaxf(m, __shfl_xor(m, 2));
        float s = 0.f, q = 0.f;
        #pragma unroll
        for (int i = 0; i < 64; ++i) { float e = __expf(v[i] - m); v[i] = e; s += e; q = fmaf(e, e, q); }
        s += __shfl_xor(s, 1); s += __shfl_xor(s, 2);
        q += __shfl_xor(q, 1); q += __shfl_xor(q, 2);
        float rs = (s > 0.f) ? 1.f / s : 0.f;
        if (p == 0) sW[r] = sqrtf(q) * rs;
        #pragma unroll
        for (int i = 0; i < 8; ++i) {
            int ck = p * 8 + i;
            short8 o;
            #pragma unroll
            for (int e = 0; e < 8; ++e) o[e] = (short)f2bfh(v[i * 8 + e] * rs);
            int byte = ((r << 9) + (ck << 4)) ^ ((r & 7) << 4);
            *(short8*)(smem + ES_A + byte) = o;
        }
    }
    __syncthreads();

    const unsigned short* Bbase =
        (c < 32) ? hfT + (((size_t)((b << 8) + (c << 3) + (lrow & 7))) << 8)
                 : peT + (((size_t)((((b << 6) + (c - 32)) << 2) + (lrow & 3))) << 8);
    f32x4 acc = (f32x4)(0.f);
    #pragma unroll
    for (int k0 = 0; k0 < 256; k0 += 32) {
        int kb = k0 + kgrp;
        int byte = ((((w << 4) + lrow) << 9) + (kb << 1)) ^ ((lrow & 7) << 4);
        short8 a = *(const short8*)(smem + ES_A + byte);
        short8 bb = *(const short8*)(Bbase + kb);
        acc = MFMA(a, bb, acc);
    }
    const int nvalid = (c < 32) ? 8 : 3;
    if (lrow < nvalid) {
        #pragma unroll
        for (int r2 = 0; r2 < 4; ++r2) {
            int ql = (w << 4) + drow + r2;
            float val = acc[r2] * sW[ql];
            size_t grow = (size_t)((b << 8) + (qc << 6) + ql);
            if (c < 32) OIb[(grow << 8) + (c << 3) + lrow] = f2bfh(val);
            else        OEb[(grow * 3 + lrow) * 64 + (c - 32)] = f2bfh(val);
        }
    }
}

// ---------------------------------------------------------------------------
// final projections (MFMA GEMMs)
// ---------------------------------------------------------------------------
constexpr int PJ_BYTES = 32768;

__launch_bounds__(256, 4)
__global__ void semla_proj(const unsigned short* __restrict__ OIb,
                           const unsigned short* __restrict__ OEb,
                           const unsigned short* __restrict__ WoT,
                           const unsigned short* __restrict__ EoT,
                           const float* __restrict__ inv_outb, float* __restrict__ out) {
    extern __shared__ char smem[];
    const int tid = threadIdx.x, lane = tid & 63, w = tid >> 6;
    const int lrow = lane & 15, kgrp = (lane >> 4) << 3, drow = (lane >> 4) << 2;
    const int bi = blockIdx.x;

    if (bi < 32) {
        const int mb = bi >> 1, nb = bi & 1;
        #pragma unroll
        for (int i = 0; i < 8; ++i) {
            int id = i * 256 + tid; int row = id >> 5, ck = id & 31;
            short8 v = *(const short8*)(OIb + (((size_t)(mb * 64 + row)) << 8) + ck * 16);
            int byte = ((row << 9) + (ck << 4)) ^ ((row & 7) << 4);
            *(short8*)(smem + byte) = v;
        }
        __syncthreads();
        f32x4 acc[4][2];
        #pragma unroll
        for (int mi = 0; mi < 4; ++mi)
            #pragma unroll
            for (int ti = 0; ti < 2; ++ti) acc[mi][ti] = (f32x4)(0.f);
        #pragma unroll
        for (int k0 = 0; k0 < 256; k0 += 32) {
            int kb = k0 + kgrp;
            short8 a[4];
            #pragma unroll
            for (int mi = 0; mi < 4; ++mi) {
                int byte = ((((mi << 4) + lrow) << 9) + (kb << 1)) ^ ((lrow & 7) << 4);
                a[mi] = *(const short8*)(smem + byte);
            }
            #pragma unroll
            for (int ti = 0; ti < 2; ++ti) {
                int n = nb * 128 + w * 32 + (ti << 4) + lrow;
                short8 bb = *(const short8*)(WoT + n * 256 + kb);
                #pragma unroll
                for (int mi = 0; mi < 4; ++mi) acc[mi][ti] = MFMA(a[mi], bb, acc[mi][ti]);
            }
        }
        #pragma unroll
        for (int ti = 0; ti < 2; ++ti) {
            int n = nb * 128 + w * 32 + (ti << 4) + lrow;
            float bias = inv_outb[n];
            #pragma unroll
            for (int mi = 0; mi < 4; ++mi)
                #pragma unroll
                for (int r = 0; r < 4; ++r) {
                    int row = mb * 64 + (mi << 4) + drow + r;
                    out[INV_OFF + (size_t)row * 256 + n] = acc[mi][ti][r] + bias;
                }
        }
    } else {
        const int mb = bi - 32;
        #pragma unroll
        for (int i = 0; i < 2; ++i) {
            int id = i * 256 + tid; int row = id >> 3, ck = id & 7;
            short8 v = *(const short8*)(OEb + (((size_t)(mb * 64 + row)) << 6) + ck * 16);
            int byte = ((row << 7) + (ck << 4)) ^ ((row & 7) << 4);
            *(short8*)(smem + byte) = v;
        }
        __syncthreads();
        f32x4 acc[4];
        #pragma unroll
        for (int ni = 0; ni < 4; ++ni) acc[ni] = (f32x4)(0.f);
        #pragma unroll
        for (int k0 = 0; k0 < 64; k0 += 32) {
            int kb = k0 + kgrp;
            int byte = ((((w << 4) + lrow) << 7) + (kb << 1)) ^ ((lrow & 7) << 4);
            short8 a = *(const short8*)(smem + byte);
            #pragma unroll
            for (int ni = 0; ni < 4; ++ni) {
                short8 bb = *(const short8*)(EoT + ((ni << 4) + lrow) * 64 + kb);
                acc[ni] = MFMA(a, bb, acc[ni]);
            }
        }
        #pragma unroll
        for (int ni = 0; ni < 4; ++ni)
            #pragma unroll
            for (int r = 0; r < 4; ++r) {
                int rowg = mb * 64 + (w << 4) + drow + r;
                int bq = rowg / 3, d = rowg - 3 * bq;
                out[EQUI_OFF + (size_t)bq * 192 + d * 64 + (ni << 4) + lrow] = acc[ni][r];
            }
    }
}

// ---------------------------------------------------------------------------
extern "C" void kernel_launch(void* const* d_in, const int* in_sizes, int n_in,
                              void* d_out, int out_size, void* d_ws, size_t ws_size,
                              hipStream_t stream) {
    const float* equis    = (const float*)d_in[0];
    const float* invs     = (const float*)d_in[1];
    const float* edges    = (const float*)d_in[2];
    const int*   adj      = (const int*)d_in[3];
    const float* qW       = (const float*)d_in[4];
    const float* qb       = (const float*)d_in[5];
    const float* kW       = (const float*)d_in[6];
    const float* kb       = (const float*)d_in[7];
    const float* mW1      = (const float*)d_in[8];
    const float* mb1      = (const float*)d_in[9];
    const float* mW2      = (const float*)d_in[10];
    const float* mb2      = (const float*)d_in[11];
    const float* inv_inW  = (const float*)d_in[12];
    const float* inv_inb  = (const float*)d_in[13];
    const float* inv_outW = (const float*)d_in[14];
    const float* inv_outb = (const float*)d_in[15];
    const float* equi_inW = (const float*)d_in[16];
    const float* equi_outW= (const float*)d_in[17];

    char* ws = (char*)d_ws;
    short* W1T = (short*)(ws + 0);                        //  64 KiB (256x128)
    short* W2T = (short*)(ws + 65536);                    //  80 KiB
    float* qm  = (float*)(ws + 147456);                   // 256 KiB
    float* km  = (float*)(ws + 409600);                   // 256 KiB
    float* hf  = (float*)(ws + 671744);                   //   1 MiB
    float* pe  = (float*)(ws + 1720320);                  // 768 KiB
    float* c1  = (float*)(ws + 2506752);                  //   1 MiB
    float* c2  = (float*)(ws + 3555328);                  //   1 MiB
    unsigned short* PT  = (unsigned short*)(ws + 4603904);   // 48 MiB
    unsigned short* peT = (unsigned short*)(ws + 54935552);  // 512 KiB
    unsigned short* hfT = (unsigned short*)(ws + 55459840);  // 512 KiB
    unsigned short* OIb = (unsigned short*)(ws + 55984128);  // 512 KiB
    unsigned short* OEb = (unsigned short*)(ws + 56508416);  // 384 KiB
    unsigned short* WoT = (unsigned short*)(ws + 56901632);  // 128 KiB
    unsigned short* EoT = (unsigned short*)(ws + 57032704);  //   8 KiB

    prep1<<<2336, 256, 0, stream>>>(invs, equis, qW, qb, kW, kb,
                                    inv_inW, inv_inb, equi_inW, mW1, mW2,
                                    qm, km, hf, pe, W1T, W2T);
    prep2<<<2193, 256, 0, stream>>>(qm, km, mW1, mb1, hf, pe, inv_outW, equi_outW,
                                    c1, c2, hfT, peT, WoT, EoT);
    semla_gemm<<<4096, 512, GA_BYTES, stream>>>(equis, edges, adj, mb2, W1T, W2T,
                                                c1, c2, (float*)d_out, PT);
    semla_einsum<<<1536, 256, ES_BYTES, stream>>>(PT, hfT, peT, OIb, OEb);
    semla_proj<<<80, 256, PJ_BYTES, stream>>>(OIb, OEb, WoT, EoT, inv_outb, (float*)d_out);
}

// Round 13
// 160.804 us; speedup vs baseline: 1.4768x; 1.4768x over previous
//
#include <hip/hip_runtime.h>
#include <hip/hip_bf16.h>
#include <math.h>

// ---------------------------------------------------------------------------
// SemlaSelfAttention — MI355X (gfx950)
// Round 13 = round 10 (best measured: total 161us, gemm 134us) +
//   (a) XCD-group swizzle in semla_gemm: blocks sharing one (b,jc) operand
//       panel (c2 64KB + equis 48KB + W 144KB) map to ONE XCD -> panel
//       becomes same-XCD L2-resident (T1 mechanism).
//   (b) s_setprio(1) around einsum MFMA chain (independent-block regime).
// Everything else byte-identical to round 10.
// ---------------------------------------------------------------------------

typedef __attribute__((ext_vector_type(8))) short short8;
typedef __attribute__((ext_vector_type(8))) __bf16 bf16x8;
typedef __attribute__((ext_vector_type(4))) float f32x4;

constexpr int EQUI_OFF = 0;          // 4*256*3*64 floats
constexpr int INV_OFF  = 196608;     // 4*256*256
constexpr int EDGE_OFF = 458752;     // 4*256*256*64

__device__ __forceinline__ unsigned short f2bf(float x) {
    unsigned u = __builtin_bit_cast(unsigned, x);
    u = u + 0x7FFFu + ((u >> 16) & 1u);   // RNE (prep kernels only)
    return (unsigned short)(u >> 16);
}
__device__ __forceinline__ float bf2f(unsigned short u) {
    return __builtin_bit_cast(float, ((unsigned)u) << 16);
}
__device__ __forceinline__ unsigned short f2bfh(float x) {   // native v_cvt (RNE)
    return __builtin_bit_cast(unsigned short, (__bf16)x);
}
__device__ __forceinline__ unsigned pk2(float a, float b) {
    return (unsigned)f2bfh(a) | ((unsigned)f2bfh(b) << 16);
}
__device__ __forceinline__ short8 pk8(f32x4 a, f32x4 b) {
    bf16x8 r = { (__bf16)a.x, (__bf16)a.y, (__bf16)a.z, (__bf16)a.w,
                 (__bf16)b.x, (__bf16)b.y, (__bf16)b.z, (__bf16)b.w };
    return __builtin_bit_cast(short8, r);
}
__device__ __forceinline__ f32x4 MFMA(short8 a, short8 b, f32x4 c) {
    return __builtin_amdgcn_mfma_f32_16x16x32_bf16(
        __builtin_bit_cast(bf16x8, a), __builtin_bit_cast(bf16x8, b), c, 0, 0, 0);
}

// ---------------------------------------------------------------------------
// prep1: projections (blocks 0..2047) + weight transposes (2048..2335)
// ---------------------------------------------------------------------------
__global__ void prep1(const float* __restrict__ invs, const float* __restrict__ equis,
                      const float* __restrict__ qW, const float* __restrict__ qb,
                      const float* __restrict__ kW, const float* __restrict__ kb,
                      const float* __restrict__ inv_inW, const float* __restrict__ inv_inb,
                      const float* __restrict__ equi_inW,
                      const float* __restrict__ mW1, const float* __restrict__ mW2,
                      float* __restrict__ qm, float* __restrict__ km,
                      float* __restrict__ hf, float* __restrict__ pe,
                      short* __restrict__ W1T, short* __restrict__ W2T) {
    int tid = threadIdx.x, bi = blockIdx.x;
    if (bi < 1024) {
        int r = bi;
        __shared__ float sInv[256];
        sInv[tid] = invs[r * 256 + tid];
        __syncthreads();
        if (tid < 64) {
            float acc = qb[tid];
            for (int f = 0; f < 256; ++f) acc += sInv[f] * qW[f * 64 + tid];
            qm[r * 64 + tid] = acc;
        } else if (tid < 128) {
            int c = tid - 64;
            float acc = kb[c];
            for (int f = 0; f < 256; ++f) acc += sInv[f] * kW[f * 64 + c];
            km[r * 64 + c] = acc;
        }
        float acch = inv_inb[tid];
        for (int f = 0; f < 256; ++f) acch += sInv[f] * inv_inW[f * 256 + tid];
        hf[r * 256 + tid] = acch;
    } else if (bi < 2048) {
        int rn = bi - 1024;
        if (tid < 192) {
            int d = tid >> 6, c = tid & 63;
            const float* erow = equis + (size_t)rn * 192 + d * 64;
            float acc = 0.f;
            for (int f = 0; f < 64; ++f) acc += erow[f] * equi_inW[f * 64 + c];
            pe[rn * 192 + d * 64 + c] = acc;
        }
    } else {
        int idx = (bi - 2048) * 256 + tid;          // 288 blocks -> 73728 elems
        if (idx < 32768) {                          // W1T[n][kk] = mW1[128+kk][n]
            int n = idx >> 7, kk = idx & 127;
            W1T[idx] = (short)f2bf(mW1[(128 + kk) * 256 + n]);
        } else {                                    // W2T[n][f] = mW2[f][n]
            int i2 = idx - 32768;
            int n = i2 >> 8, f = i2 & 255;
            W2T[i2] = (short)f2bf(mW2[f * 160 + n]);
        }
    }
}

// ---------------------------------------------------------------------------
// prep2: c1/c2 folds (blocks 0..2047) + bf16 transposes (2048..2192)
// ---------------------------------------------------------------------------
__global__ void prep2(const float* __restrict__ qm, const float* __restrict__ km,
                      const float* __restrict__ mW1, const float* __restrict__ mb1,
                      const float* __restrict__ hf, const float* __restrict__ pe,
                      const float* __restrict__ inv_outW, const float* __restrict__ equi_outW,
                      float* __restrict__ c1, float* __restrict__ c2,
                      unsigned short* __restrict__ hfT, unsigned short* __restrict__ peT,
                      unsigned short* __restrict__ WoT, unsigned short* __restrict__ EoT) {
    __shared__ float sT[64][65];
    int tid = threadIdx.x, bi = blockIdx.x;
    if (bi < 1024) {
        int r = bi;
        if (tid < 64) sT[0][tid] = qm[r * 64 + tid];
        __syncthreads();
        float acc = mb1[tid];
        #pragma unroll 8
        for (int k = 0; k < 64; ++k) acc = fmaf(sT[0][k], mW1[k * 256 + tid], acc);
        c1[r * 256 + tid] = acc;
    } else if (bi < 2048) {
        int r = bi - 1024;
        if (tid < 64) sT[0][tid] = km[r * 64 + tid];
        __syncthreads();
        float acc = 0.f;
        #pragma unroll 8
        for (int k = 0; k < 64; ++k) acc = fmaf(sT[0][k], mW1[(64 + k) * 256 + tid], acc);
        c2[r * 256 + tid] = acc;
    } else {
        int bt = bi - 2048;
        if (bt < 64) {            // hfT[b][hd][j] = hf[b,j,hd]
            int b = bt >> 4, t = bt & 15, tj = t >> 2, th = t & 3;
            #pragma unroll
            for (int i = 0; i < 16; ++i) { int idx = i * 256 + tid; int jl = idx >> 6, hl = idx & 63;
                sT[jl][hl] = hf[((size_t)(b * 256 + tj * 64 + jl)) * 256 + th * 64 + hl]; }
            __syncthreads();
            #pragma unroll
            for (int i = 0; i < 16; ++i) { int idx = i * 256 + tid; int hl = idx >> 6, jl = idx & 63;
                hfT[((size_t)(b * 256 + th * 64 + hl)) * 256 + tj * 64 + jl] = f2bf(sT[jl][hl]); }
        } else if (bt < 128) {    // peT[b][c][d][j] = pe[b,j,d,c]; d=3 zeroed
            int i2 = bt - 64; int b = i2 >> 4, t = i2 & 15, tj = t >> 2, d = t & 3;
            if (d == 3) {
                #pragma unroll
                for (int i = 0; i < 16; ++i) { int idx = i * 256 + tid; int c = idx >> 6, jl = idx & 63;
                    peT[((size_t)((b * 64 + c) * 4 + 3)) * 256 + tj * 64 + jl] = 0; }
            } else {
                #pragma unroll
                for (int i = 0; i < 16; ++i) { int idx = i * 256 + tid; int jl = idx >> 6, c = idx & 63;
                    sT[jl][c] = pe[((size_t)(b * 256 + tj * 64 + jl)) * 192 + d * 64 + c]; }
                __syncthreads();
                #pragma unroll
                for (int i = 0; i < 16; ++i) { int idx = i * 256 + tid; int c = idx >> 6, jl = idx & 63;
                    peT[((size_t)((b * 64 + c) * 4 + d)) * 256 + tj * 64 + jl] = f2bf(sT[jl][c]); }
            }
        } else if (bt < 144) {    // WoT[n][f] = inv_outW[f][n]
            int i2 = bt - 128; int tf = i2 >> 2, tn = i2 & 3;
            #pragma unroll
            for (int i = 0; i < 16; ++i) { int idx = i * 256 + tid; int fl = idx >> 6, nl = idx & 63;
                sT[fl][nl] = inv_outW[(size_t)(tf * 64 + fl) * 256 + tn * 64 + nl]; }
            __syncthreads();
            #pragma unroll
            for (int i = 0; i < 16; ++i) { int idx = i * 256 + tid; int nl = idx >> 6, fl = idx & 63;
                WoT[(size_t)(tn * 64 + nl) * 256 + tf * 64 + fl] = f2bf(sT[fl][nl]); }
        } else {                  // EoT[c'][c] = equi_outW[c][c']
            #pragma unroll
            for (int i = 0; i < 16; ++i) { int idx = i * 256 + tid; int cl = idx >> 6, c2i = idx & 63;
                sT[cl][c2i] = equi_outW[cl * 64 + c2i]; }
            __syncthreads();
            #pragma unroll
            for (int i = 0; i < 16; ++i) { int idx = i * 256 + tid; int c2i = idx >> 6, cl = idx & 63;
                EoT[c2i * 64 + cl] = f2bf(sT[cl][c2i]); }
        }
    }
}

// ---------------------------------------------------------------------------
// GEMM kernel: one block per (b,q,jc); 4 waves; ~34 KB LDS -> 4 blocks/CU
// XCD-group swizzle: group g=(b,jc) -> XCD g&7; each XCD's L2 holds its
// groups' shared panels (c2 slice, equis slice, W1T/W2T).
// ---------------------------------------------------------------------------
constexpr int GA_AH   = 0;        // A: 64x128 bf16 (16K) / H: 64x256 (32K) / sPT 96x136B
constexpr int GA_EQ   = 32768;    // 192 f32
constexpr int GA_MASK = 33536;    // 64 f32
constexpr int GA_BYTES = 33792;

__launch_bounds__(256, 4)
__global__ void semla_gemm(const float* __restrict__ equis, const float* __restrict__ edges,
                           const int* __restrict__ adj, const float* __restrict__ mb2,
                           const short* __restrict__ W1T, const short* __restrict__ W2T,
                           const float* __restrict__ c1, const float* __restrict__ c2,
                           float* __restrict__ out, unsigned short* __restrict__ PT) {
    extern __shared__ char smem[];
    float* sEQ   = (float*)(smem + GA_EQ);
    float* sMask = (float*)(smem + GA_MASK);

    const int tid  = threadIdx.x;
    const int lane = tid & 63;
    const int w    = tid >> 6;
    // XCD-group swizzle (bijective, grid 4096):
    //   x = bid&7 (XCD), t = bid>>3; q = t&255; g = x + 8*(t>>8) in 0..15
    //   b = g>>2, jc = g&3 -> all 256 blocks of group (b,jc) land on XCD x.
    const int bid  = blockIdx.x;
    const int xg   = bid & 7;
    const int tg   = bid >> 3;
    const int g    = xg + ((tg >> 8) << 3);
    const int b    = g >> 2;
    const int jc   = g & 3;
    const int bq   = (b << 8) + (tg & 255);

    const int lrow = lane & 15;
    const int kgrp = (lane >> 4) << 3;
    const int drow = (lane >> 4) << 2;

    if (tid < 192) sEQ[tid] = equis[(size_t)bq * 192 + tid];
    if (tid < 64)  sMask[tid] = adj[(size_t)bq * 256 + (jc << 6) + tid] ? 0.f : -1e30f;

    float c1v[4];
    #pragma unroll
    for (int ni = 0; ni < 4; ++ni)
        c1v[ni] = c1[bq * 256 + (w << 6) + (ni << 4) + lrow];
    const int ntiles = (w < 2) ? 3 : 2;
    const int nbase  = (w < 2) ? w * 48 : 96 + (w - 2) * 32;
    float b2v[3];
    #pragma unroll
    for (int ti = 0; ti < 3; ++ti)
        if (ti < ntiles) b2v[ti] = mb2[nbase + (ti << 4) + lrow];

    // LDS helpers (XOR-swizzled)
    auto stA16 = [&](int row, int colbyte, short8 v) {   // A [64][128] bf16
        int byte = ((row << 8) + colbyte) ^ ((row & 7) << 4);
        *(short8*)(smem + GA_AH + byte) = v;
    };
    auto ldA = [&](int row, int kb) -> short8 {
        int byte = ((row << 8) + (kb << 1)) ^ ((row & 7) << 4);
        return *(const short8*)(smem + GA_AH + byte);
    };
    auto stH = [&](int row, int col, unsigned short v) { // H [64][256] bf16
        int byte = ((row << 9) + (col << 1)) ^ ((row & 7) << 4);
        *(unsigned short*)(smem + GA_AH + byte) = v;
    };
    auto ldH = [&](int row, int kb) -> short8 {
        int byte = ((row << 9) + (kb << 1)) ^ ((row & 7) << 4);
        return *(const short8*)(smem + GA_AH + byte);
    };

    __syncthreads();   // sEQ/sMask visible

    // ---- build A: cols 0..63 = dot(q,j), 64..127 = edges[b,q,j] (16B stores) ----
    {
        int r = tid >> 2, h = tid & 3;
        const float* erow = equis + (size_t)((b << 8) + (jc << 6) + r) * 192;
        #pragma unroll
        for (int g2 = 0; g2 < 2; ++g2) {
            int cg = h + g2 * 4;                // 8-col group of dot
            f32x4 lo = (f32x4)(0.f), hi = (f32x4)(0.f);
            #pragma unroll
            for (int d = 0; d < 3; ++d) {
                f32x4 e0 = *(const f32x4*)(erow + d * 64 + cg * 8);
                f32x4 e1 = *(const f32x4*)(erow + d * 64 + cg * 8 + 4);
                f32x4 q0 = *(const f32x4*)(sEQ + d * 64 + cg * 8);
                f32x4 q1 = *(const f32x4*)(sEQ + d * 64 + cg * 8 + 4);
                lo += e0 * q0; hi += e1 * q1;
            }
            stA16(r, cg * 16, pk8(lo, hi));
        }
        const float* ebase = edges + ((size_t)bq * 256 + (jc << 6)) * 64;
        #pragma unroll
        for (int g2 = 0; g2 < 2; ++g2) {
            int c8 = h + g2 * 4;                // 8-col group of edges
            f32x4 e0 = *(const f32x4*)(ebase + r * 64 + c8 * 8);
            f32x4 e1 = *(const f32x4*)(ebase + r * 64 + c8 * 8 + 4);
            stA16(r, 128 + c8 * 16, pk8(e0, e1));
        }
    }
    __syncthreads();

    // ---- GEMM1: H = silu(A @ W1[128:] + c1 + c2), K=128 ----
    f32x4 acc[4][4];
    #pragma unroll
    for (int mi = 0; mi < 4; ++mi)
        #pragma unroll
        for (int ni = 0; ni < 4; ++ni) acc[mi][ni] = (f32x4)(0.f);

    #pragma unroll
    for (int k0 = 0; k0 < 128; k0 += 32) {
        int kb = k0 + kgrp;
        short8 a0 = ldA(lrow, kb), a1 = ldA(16 + lrow, kb),
               a2 = ldA(32 + lrow, kb), a3 = ldA(48 + lrow, kb);
        short8 bf[4];
        #pragma unroll
        for (int ni = 0; ni < 4; ++ni)
            bf[ni] = *(const short8*)(W1T + ((w << 6) + (ni << 4) + lrow) * 128 + kb);
        #pragma unroll
        for (int ni = 0; ni < 4; ++ni) {
            acc[0][ni] = MFMA(a0, bf[ni], acc[0][ni]);
            acc[1][ni] = MFMA(a1, bf[ni], acc[1][ni]);
            acc[2][ni] = MFMA(a2, bf[ni], acc[2][ni]);
            acc[3][ni] = MFMA(a3, bf[ni], acc[3][ni]);
        }
    }
    __syncthreads();   // all waves done reading A (H aliases A)

    const float* c2base = c2 + ((size_t)((b << 8) + (jc << 6)) << 8);
    #pragma unroll
    for (int mi = 0; mi < 4; ++mi)
        #pragma unroll
        for (int r = 0; r < 4; ++r) {
            int row = (mi << 4) + drow + r;
            const float* c2row = c2base + (row << 8);
            #pragma unroll
            for (int ni = 0; ni < 4; ++ni) {
                int n = (w << 6) + (ni << 4) + lrow;
                float x = acc[mi][ni][r] + c1v[ni] + c2row[n];
                float hh = x * __builtin_amdgcn_rcpf(1.f + __expf(-x));
                stH(row, n, f2bfh(hh));
            }
        }
    __syncthreads();

    // ---- GEMM2: msgs = H @ W2 + b2 ; n-tiles 3/3/2/2 across waves ----
    f32x4 acc2[4][3];
    #pragma unroll
    for (int mi = 0; mi < 4; ++mi)
        #pragma unroll
        for (int ti = 0; ti < 3; ++ti) acc2[mi][ti] = (f32x4)(0.f);

    #pragma unroll
    for (int k0 = 0; k0 < 256; k0 += 32) {
        int kb = k0 + kgrp;
        short8 a0 = ldH(lrow, kb), a1 = ldH(16 + lrow, kb),
               a2 = ldH(32 + lrow, kb), a3 = ldH(48 + lrow, kb);
        short8 bt[3];
        #pragma unroll
        for (int ti = 0; ti < 3; ++ti)
            if (ti < ntiles) bt[ti] = *(const short8*)(W2T + (nbase + (ti << 4) + lrow) * 256 + kb);
        #pragma unroll
        for (int ti = 0; ti < 3; ++ti)
            if (ti < ntiles) {
                acc2[0][ti] = MFMA(a0, bt[ti], acc2[0][ti]);
                acc2[1][ti] = MFMA(a1, bt[ti], acc2[1][ti]);
                acc2[2][ti] = MFMA(a2, bt[ti], acc2[2][ti]);
                acc2[3][ti] = MFMA(a3, bt[ti], acc2[3][ti]);
            }
    }
    __syncthreads();   // H fully consumed; smem[0..13056) reused as sPT[96][136B]

    if (w < 2) {
        // attn cols: bias + mask -> bf16 -> transposed LDS tile (packed u32 stores)
        #pragma unroll
        for (int ti = 0; ti < 3; ++ti) {
            int n = nbase + (ti << 4) + lrow;
            float bias = b2v[ti];
            #pragma unroll
            for (int mi = 0; mi < 4; ++mi) {
                int j0 = (mi << 4) + drow;
                f32x4 mv = *(const f32x4*)(sMask + j0);
                unsigned lo = pk2(acc2[mi][ti][0] + bias + mv.x,
                                  acc2[mi][ti][1] + bias + mv.y);
                unsigned hi = pk2(acc2[mi][ti][2] + bias + mv.z,
                                  acc2[mi][ti][3] + bias + mv.w);
                *(unsigned*)(smem + n * 136 + j0 * 2)     = lo;
                *(unsigned*)(smem + n * 136 + j0 * 2 + 4) = hi;
            }
        }
    } else {
        // edge cols: straight f32 to out
        #pragma unroll
        for (int mi = 0; mi < 4; ++mi)
            #pragma unroll
            for (int ti = 0; ti < 2; ++ti) {
                int n = nbase + (ti << 4) + lrow;
                #pragma unroll
                for (int r = 0; r < 4; ++r) {
                    int j = (jc << 6) + (mi << 4) + drow + r;
                    out[EDGE_OFF + ((size_t)bq * 256 + j) * 64 + (n - 96)] = acc2[mi][ti][r] + b2v[ti];
                }
            }
    }
    __syncthreads();

    // coalesced PT store: PT[bq*96+n][jc*64 .. +64] (64B per thread)
    if (tid < 192) {
        int n = tid >> 1, half = tid & 1;
        const char* src = smem + n * 136 + half * 64;
        unsigned short* dst = PT + (((size_t)bq * 96 + n) << 8) + (jc << 6) + half * 32;
        #pragma unroll
        for (int i = 0; i < 4; ++i)
            *(short8*)(dst + i * 8) = *(const short8*)(src + i * 16);
    }
}

// ---------------------------------------------------------------------------
// einsum kernel: one block per (b, c, qc); softmax in regs + 1 MFMA chain
// ---------------------------------------------------------------------------
constexpr int ES_A = 0;        // 64x256 bf16 swizzled = 32768
constexpr int ES_W = 32768;    // 64 f32
constexpr int ES_BYTES = 33024;

__launch_bounds__(256, 4)
__global__ void semla_einsum(const unsigned short* __restrict__ PT,
                             const unsigned short* __restrict__ hfT,
                             const unsigned short* __restrict__ peT,
                             unsigned short* __restrict__ OIb, unsigned short* __restrict__ OEb) {
    extern __shared__ char smem[];
    float* sW = (float*)(smem + ES_W);
    const int tid = threadIdx.x, lane = tid & 63, w = tid >> 6;
    const int bi = blockIdx.x;
    const int qc = bi & 3;
    const int t  = bi >> 2;
    const int b  = t / 96;
    const int c  = t - 96 * b;
    const int lrow = lane & 15, kgrp = (lane >> 4) << 3, drow = (lane >> 4) << 2;

    #pragma unroll
    for (int i = 0; i < 8; ++i) {
        int id = i * 256 + tid; int row = id >> 5, ck = id & 31;
        size_t src = (((size_t)((b << 8) + (qc << 6) + row) * 96 + c) << 8) + ck * 16;
        short8 v = *(const short8*)(PT + src);
        int byte = ((row << 9) + (ck << 4)) ^ ((row & 7) << 4);
        *(short8*)(smem + ES_A + byte) = v;
    }
    __syncthreads();

    {   // softmax: row r = tid>>2, 4 threads/row, 64 elems each, in registers
        int r = tid >> 2, p = tid & 3;
        float v[64];
        #pragma unroll
        for (int i = 0; i < 8; ++i) {
            int ck = p * 8 + i;
            int byte = ((r << 9) + (ck << 4)) ^ ((r & 7) << 4);
            short8 x = *(const short8*)(smem + ES_A + byte);
            #pragma unroll
            for (int e = 0; e < 8; ++e) v[i * 8 + e] = bf2f((unsigned short)x[e]);
        }
        float m = v[0];
        #pragma unroll
        for (int i = 1; i < 64; ++i) m = fmaxf(m, v[i]);
        m = fmaxf(m, __shfl_xor(m, 1)); m = fmaxf(m, __shfl_xor(m, 2));
        float s = 0.f, q = 0.f;
        #pragma unroll
        for (int i = 0; i < 64; ++i) { float e = __expf(v[i] - m); v[i] = e; s += e; q = fmaf(e, e, q); }
        s += __shfl_xor(s, 1); s += __shfl_xor(s, 2);
        q += __shfl_xor(q, 1); q += __shfl_xor(q, 2);
        float rs = (s > 0.f) ? 1.f / s : 0.f;
        if (p == 0) sW[r] = sqrtf(q) * rs;
        #pragma unroll
        for (int i = 0; i < 8; ++i) {
            int ck = p * 8 + i;
            short8 o;
            #pragma unroll
            for (int e = 0; e < 8; ++e) o[e] = (short)f2bfh(v[i * 8 + e] * rs);
            int byte = ((r << 9) + (ck << 4)) ^ ((r & 7) << 4);
            *(short8*)(smem + ES_A + byte) = o;
        }
    }
    __syncthreads();

    const unsigned short* Bbase =
        (c < 32) ? hfT + (((size_t)((b << 8) + (c << 3) + (lrow & 7))) << 8)
                 : peT + (((size_t)((((b << 6) + (c - 32)) << 2) + (lrow & 3))) << 8);
    f32x4 acc = (f32x4)(0.f);
    __builtin_amdgcn_s_setprio(1);
    #pragma unroll
    for (int k0 = 0; k0 < 256; k0 += 32) {
        int kb = k0 + kgrp;
        int byte = ((((w << 4) + lrow) << 9) + (kb << 1)) ^ ((lrow & 7) << 4);
        short8 a = *(const short8*)(smem + ES_A + byte);
        short8 bb = *(const short8*)(Bbase + kb);
        acc = MFMA(a, bb, acc);
    }
    __builtin_amdgcn_s_setprio(0);
    const int nvalid = (c < 32) ? 8 : 3;
    if (lrow < nvalid) {
        #pragma unroll
        for (int r2 = 0; r2 < 4; ++r2) {
            int ql = (w << 4) + drow + r2;
            float val = acc[r2] * sW[ql];
            size_t grow = (size_t)((b << 8) + (qc << 6) + ql);
            if (c < 32) OIb[(grow << 8) + (c << 3) + lrow] = f2bfh(val);
            else        OEb[(grow * 3 + lrow) * 64 + (c - 32)] = f2bfh(val);
        }
    }
}

// ---------------------------------------------------------------------------
// final projections (MFMA GEMMs)
// ---------------------------------------------------------------------------
constexpr int PJ_BYTES = 32768;

__launch_bounds__(256, 4)
__global__ void semla_proj(const unsigned short* __restrict__ OIb,
                           const unsigned short* __restrict__ OEb,
                           const unsigned short* __restrict__ WoT,
                           const unsigned short* __restrict__ EoT,
                           const float* __restrict__ inv_outb, float* __restrict__ out) {
    extern __shared__ char smem[];
    const int tid = threadIdx.x, lane = tid & 63, w = tid >> 6;
    const int lrow = lane & 15, kgrp = (lane >> 4) << 3, drow = (lane >> 4) << 2;
    const int bi = blockIdx.x;

    if (bi < 32) {
        const int mb = bi >> 1, nb = bi & 1;
        #pragma unroll
        for (int i = 0; i < 8; ++i) {
            int id = i * 256 + tid; int row = id >> 5, ck = id & 31;
            short8 v = *(const short8*)(OIb + (((size_t)(mb * 64 + row)) << 8) + ck * 16);
            int byte = ((row << 9) + (ck << 4)) ^ ((row & 7) << 4);
            *(short8*)(smem + byte) = v;
        }
        __syncthreads();
        f32x4 acc[4][2];
        #pragma unroll
        for (int mi = 0; mi < 4; ++mi)
            #pragma unroll
            for (int ti = 0; ti < 2; ++ti) acc[mi][ti] = (f32x4)(0.f);
        #pragma unroll
        for (int k0 = 0; k0 < 256; k0 += 32) {
            int kb = k0 + kgrp;
            short8 a[4];
            #pragma unroll
            for (int mi = 0; mi < 4; ++mi) {
                int byte = ((((mi << 4) + lrow) << 9) + (kb << 1)) ^ ((lrow & 7) << 4);
                a[mi] = *(const short8*)(smem + byte);
            }
            #pragma unroll
            for (int ti = 0; ti < 2; ++ti) {
                int n = nb * 128 + w * 32 + (ti << 4) + lrow;
                short8 bb = *(const short8*)(WoT + n * 256 + kb);
                #pragma unroll
                for (int mi = 0; mi < 4; ++mi) acc[mi][ti] = MFMA(a[mi], bb, acc[mi][ti]);
            }
        }
        #pragma unroll
        for (int ti = 0; ti < 2; ++ti) {
            int n = nb * 128 + w * 32 + (ti << 4) + lrow;
            float bias = inv_outb[n];
            #pragma unroll
            for (int mi = 0; mi < 4; ++mi)
                #pragma unroll
                for (int r = 0; r < 4; ++r) {
                    int row = mb * 64 + (mi << 4) + drow + r;
                    out[INV_OFF + (size_t)row * 256 + n] = acc[mi][ti][r] + bias;
                }
        }
    } else {
        const int mb = bi - 32;
        #pragma unroll
        for (int i = 0; i < 2; ++i) {
            int id = i * 256 + tid; int row = id >> 3, ck = id & 7;
            short8 v = *(const short8*)(OEb + (((size_t)(mb * 64 + row)) << 6) + ck * 16);
            int byte = ((row << 7) + (ck << 4)) ^ ((row & 7) << 4);
            *(short8*)(smem + byte) = v;
        }
        __syncthreads();
        f32x4 acc[4];
        #pragma unroll
        for (int ni = 0; ni < 4; ++ni) acc[ni] = (f32x4)(0.f);
        #pragma unroll
        for (int k0 = 0; k0 < 64; k0 += 32) {
            int kb = k0 + kgrp;
            int byte = ((((w << 4) + lrow) << 7) + (kb << 1)) ^ ((lrow & 7) << 4);
            short8 a = *(const short8*)(smem + byte);
            #pragma unroll
            for (int ni = 0; ni < 4; ++ni) {
                short8 bb = *(const short8*)(EoT + ((ni << 4) + lrow) * 64 + kb);
                acc[ni] = MFMA(a, bb, acc[ni]);
            }
        }
        #pragma unroll
        for (int ni = 0; ni < 4; ++ni)
            #pragma unroll
            for (int r = 0; r < 4; ++r) {
                int rowg = mb * 64 + (w << 4) + drow + r;
                int bq = rowg / 3, d = rowg - 3 * bq;
                out[EQUI_OFF + (size_t)bq * 192 + d * 64 + (ni << 4) + lrow] = acc[ni][r];
            }
    }
}

// ---------------------------------------------------------------------------
extern "C" void kernel_launch(void* const* d_in, const int* in_sizes, int n_in,
                              void* d_out, int out_size, void* d_ws, size_t ws_size,
                              hipStream_t stream) {
    const float* equis    = (const float*)d_in[0];
    const float* invs     = (const float*)d_in[1];
    const float* edges    = (const float*)d_in[2];
    const int*   adj      = (const int*)d_in[3];
    const float* qW       = (const float*)d_in[4];
    const float* qb       = (const float*)d_in[5];
    const float* kW       = (const float*)d_in[6];
    const float* kb       = (const float*)d_in[7];
    const float* mW1      = (const float*)d_in[8];
    const float* mb1      = (const float*)d_in[9];
    const float* mW2      = (const float*)d_in[10];
    const float* mb2      = (const float*)d_in[11];
    const float* inv_inW  = (const float*)d_in[12];
    const float* inv_inb  = (const float*)d_in[13];
    const float* inv_outW = (const float*)d_in[14];
    const float* inv_outb = (const float*)d_in[15];
    const float* equi_inW = (const float*)d_in[16];
    const float* equi_outW= (const float*)d_in[17];

    char* ws = (char*)d_ws;
    short* W1T = (short*)(ws + 0);                        //  64 KiB (256x128)
    short* W2T = (short*)(ws + 65536);                    //  80 KiB
    float* qm  = (float*)(ws + 147456);                   // 256 KiB
    float* km  = (float*)(ws + 409600);                   // 256 KiB
    float* hf  = (float*)(ws + 671744);                   //   1 MiB
    float* pe  = (float*)(ws + 1720320);                  // 768 KiB
    float* c1  = (float*)(ws + 2506752);                  //   1 MiB
    float* c2  = (float*)(ws + 3555328);                  //   1 MiB
    unsigned short* PT  = (unsigned short*)(ws + 4603904);   // 48 MiB
    unsigned short* peT = (unsigned short*)(ws + 54935552);  // 512 KiB
    unsigned short* hfT = (unsigned short*)(ws + 55459840);  // 512 KiB
    unsigned short* OIb = (unsigned short*)(ws + 55984128);  // 512 KiB
    unsigned short* OEb = (unsigned short*)(ws + 56508416);  // 384 KiB
    unsigned short* WoT = (unsigned short*)(ws + 56901632);  // 128 KiB
    unsigned short* EoT = (unsigned short*)(ws + 57032704);  //   8 KiB

    prep1<<<2336, 256, 0, stream>>>(invs, equis, qW, qb, kW, kb,
                                    inv_inW, inv_inb, equi_inW, mW1, mW2,
                                    qm, km, hf, pe, W1T, W2T);
    prep2<<<2193, 256, 0, stream>>>(qm, km, mW1, mb1, hf, pe, inv_outW, equi_outW,
                                    c1, c2, hfT, peT, WoT, EoT);
    semla_gemm<<<4096, 256, GA_BYTES, stream>>>(equis, edges, adj, mb2, W1T, W2T,
                                                c1, c2, (float*)d_out, PT);
    semla_einsum<<<1536, 256, ES_BYTES, stream>>>(PT, hfT, peT, OIb, OEb);
    semla_proj<<<80, 256, PJ_BYTES, stream>>>(OIb, OEb, WoT, EoT, inv_outb, (float*)d_out);
}

// Round 14
// 157.703 us; speedup vs baseline: 1.5058x; 1.0197x over previous
//
#include <hip/hip_runtime.h>
#include <hip/hip_bf16.h>
#include <math.h>

// ---------------------------------------------------------------------------
// SemlaSelfAttention — MI355X (gfx950)
// Round 14 = round 13 (best: 160.8us; gemm plateau 134us confirmed over 8
//            structural probes) + ILP micro-fixes on the non-gemm path:
//   (1) einsum softmax: tree max / 4-way partial sums (was 64-deep chains)
//   (2) prep1: 4-way partial-sum projections (was 256-deep FMA chains)
//   (3) prep2: 2-way partial c1/c2 folds
// gemm / proj / layouts byte-identical to round 13.
// ---------------------------------------------------------------------------

typedef __attribute__((ext_vector_type(8))) short short8;
typedef __attribute__((ext_vector_type(8))) __bf16 bf16x8;
typedef __attribute__((ext_vector_type(4))) float f32x4;

constexpr int EQUI_OFF = 0;          // 4*256*3*64 floats
constexpr int INV_OFF  = 196608;     // 4*256*256
constexpr int EDGE_OFF = 458752;     // 4*256*256*64

__device__ __forceinline__ unsigned short f2bf(float x) {
    unsigned u = __builtin_bit_cast(unsigned, x);
    u = u + 0x7FFFu + ((u >> 16) & 1u);   // RNE (prep kernels only)
    return (unsigned short)(u >> 16);
}
__device__ __forceinline__ float bf2f(unsigned short u) {
    return __builtin_bit_cast(float, ((unsigned)u) << 16);
}
__device__ __forceinline__ unsigned short f2bfh(float x) {   // native v_cvt (RNE)
    return __builtin_bit_cast(unsigned short, (__bf16)x);
}
__device__ __forceinline__ unsigned pk2(float a, float b) {
    return (unsigned)f2bfh(a) | ((unsigned)f2bfh(b) << 16);
}
__device__ __forceinline__ short8 pk8(f32x4 a, f32x4 b) {
    bf16x8 r = { (__bf16)a.x, (__bf16)a.y, (__bf16)a.z, (__bf16)a.w,
                 (__bf16)b.x, (__bf16)b.y, (__bf16)b.z, (__bf16)b.w };
    return __builtin_bit_cast(short8, r);
}
__device__ __forceinline__ f32x4 MFMA(short8 a, short8 b, f32x4 c) {
    return __builtin_amdgcn_mfma_f32_16x16x32_bf16(
        __builtin_bit_cast(bf16x8, a), __builtin_bit_cast(bf16x8, b), c, 0, 0, 0);
}

// ---------------------------------------------------------------------------
// prep1: projections (blocks 0..2047) + weight transposes (2048..2335)
// ---------------------------------------------------------------------------
__global__ void prep1(const float* __restrict__ invs, const float* __restrict__ equis,
                      const float* __restrict__ qW, const float* __restrict__ qb,
                      const float* __restrict__ kW, const float* __restrict__ kb,
                      const float* __restrict__ inv_inW, const float* __restrict__ inv_inb,
                      const float* __restrict__ equi_inW,
                      const float* __restrict__ mW1, const float* __restrict__ mW2,
                      float* __restrict__ qm, float* __restrict__ km,
                      float* __restrict__ hf, float* __restrict__ pe,
                      short* __restrict__ W1T, short* __restrict__ W2T) {
    int tid = threadIdx.x, bi = blockIdx.x;
    if (bi < 1024) {
        int r = bi;
        __shared__ float sInv[256];
        sInv[tid] = invs[r * 256 + tid];
        __syncthreads();
        if (tid < 64) {
            float a0 = 0.f, a1 = 0.f, a2 = 0.f, a3 = 0.f;
            #pragma unroll 4
            for (int f = 0; f < 256; f += 4) {
                a0 = fmaf(sInv[f],     qW[(f)     * 64 + tid], a0);
                a1 = fmaf(sInv[f + 1], qW[(f + 1) * 64 + tid], a1);
                a2 = fmaf(sInv[f + 2], qW[(f + 2) * 64 + tid], a2);
                a3 = fmaf(sInv[f + 3], qW[(f + 3) * 64 + tid], a3);
            }
            qm[r * 64 + tid] = qb[tid] + (a0 + a1) + (a2 + a3);
        } else if (tid < 128) {
            int c = tid - 64;
            float a0 = 0.f, a1 = 0.f, a2 = 0.f, a3 = 0.f;
            #pragma unroll 4
            for (int f = 0; f < 256; f += 4) {
                a0 = fmaf(sInv[f],     kW[(f)     * 64 + c], a0);
                a1 = fmaf(sInv[f + 1], kW[(f + 1) * 64 + c], a1);
                a2 = fmaf(sInv[f + 2], kW[(f + 2) * 64 + c], a2);
                a3 = fmaf(sInv[f + 3], kW[(f + 3) * 64 + c], a3);
            }
            km[r * 64 + c] = kb[c] + (a0 + a1) + (a2 + a3);
        }
        {
            float a0 = 0.f, a1 = 0.f, a2 = 0.f, a3 = 0.f;
            #pragma unroll 4
            for (int f = 0; f < 256; f += 4) {
                a0 = fmaf(sInv[f],     inv_inW[(f)     * 256 + tid], a0);
                a1 = fmaf(sInv[f + 1], inv_inW[(f + 1) * 256 + tid], a1);
                a2 = fmaf(sInv[f + 2], inv_inW[(f + 2) * 256 + tid], a2);
                a3 = fmaf(sInv[f + 3], inv_inW[(f + 3) * 256 + tid], a3);
            }
            hf[r * 256 + tid] = inv_inb[tid] + (a0 + a1) + (a2 + a3);
        }
    } else if (bi < 2048) {
        int rn = bi - 1024;
        if (tid < 192) {
            int d = tid >> 6, c = tid & 63;
            const float* erow = equis + (size_t)rn * 192 + d * 64;
            float a0 = 0.f, a1 = 0.f, a2 = 0.f, a3 = 0.f;
            #pragma unroll 4
            for (int f = 0; f < 64; f += 4) {
                a0 = fmaf(erow[f],     equi_inW[(f)     * 64 + c], a0);
                a1 = fmaf(erow[f + 1], equi_inW[(f + 1) * 64 + c], a1);
                a2 = fmaf(erow[f + 2], equi_inW[(f + 2) * 64 + c], a2);
                a3 = fmaf(erow[f + 3], equi_inW[(f + 3) * 64 + c], a3);
            }
            pe[rn * 192 + d * 64 + c] = (a0 + a1) + (a2 + a3);
        }
    } else {
        int idx = (bi - 2048) * 256 + tid;          // 288 blocks -> 73728 elems
        if (idx < 32768) {                          // W1T[n][kk] = mW1[128+kk][n]
            int n = idx >> 7, kk = idx & 127;
            W1T[idx] = (short)f2bf(mW1[(128 + kk) * 256 + n]);
        } else {                                    // W2T[n][f] = mW2[f][n]
            int i2 = idx - 32768;
            int n = i2 >> 8, f = i2 & 255;
            W2T[i2] = (short)f2bf(mW2[f * 160 + n]);
        }
    }
}

// ---------------------------------------------------------------------------
// prep2: c1/c2 folds (blocks 0..2047) + bf16 transposes (2048..2192)
// ---------------------------------------------------------------------------
__global__ void prep2(const float* __restrict__ qm, const float* __restrict__ km,
                      const float* __restrict__ mW1, const float* __restrict__ mb1,
                      const float* __restrict__ hf, const float* __restrict__ pe,
                      const float* __restrict__ inv_outW, const float* __restrict__ equi_outW,
                      float* __restrict__ c1, float* __restrict__ c2,
                      unsigned short* __restrict__ hfT, unsigned short* __restrict__ peT,
                      unsigned short* __restrict__ WoT, unsigned short* __restrict__ EoT) {
    __shared__ float sT[64][65];
    int tid = threadIdx.x, bi = blockIdx.x;
    if (bi < 1024) {
        int r = bi;
        if (tid < 64) sT[0][tid] = qm[r * 64 + tid];
        __syncthreads();
        float a0 = 0.f, a1 = 0.f;
        #pragma unroll 8
        for (int k = 0; k < 64; k += 2) {
            a0 = fmaf(sT[0][k],     mW1[(k)     * 256 + tid], a0);
            a1 = fmaf(sT[0][k + 1], mW1[(k + 1) * 256 + tid], a1);
        }
        c1[r * 256 + tid] = mb1[tid] + a0 + a1;
    } else if (bi < 2048) {
        int r = bi - 1024;
        if (tid < 64) sT[0][tid] = km[r * 64 + tid];
        __syncthreads();
        float a0 = 0.f, a1 = 0.f;
        #pragma unroll 8
        for (int k = 0; k < 64; k += 2) {
            a0 = fmaf(sT[0][k],     mW1[(64 + k)     * 256 + tid], a0);
            a1 = fmaf(sT[0][k + 1], mW1[(64 + k + 1) * 256 + tid], a1);
        }
        c2[r * 256 + tid] = a0 + a1;
    } else {
        int bt = bi - 2048;
        if (bt < 64) {            // hfT[b][hd][j] = hf[b,j,hd]
            int b = bt >> 4, t = bt & 15, tj = t >> 2, th = t & 3;
            #pragma unroll
            for (int i = 0; i < 16; ++i) { int idx = i * 256 + tid; int jl = idx >> 6, hl = idx & 63;
                sT[jl][hl] = hf[((size_t)(b * 256 + tj * 64 + jl)) * 256 + th * 64 + hl]; }
            __syncthreads();
            #pragma unroll
            for (int i = 0; i < 16; ++i) { int idx = i * 256 + tid; int hl = idx >> 6, jl = idx & 63;
                hfT[((size_t)(b * 256 + th * 64 + hl)) * 256 + tj * 64 + jl] = f2bf(sT[jl][hl]); }
        } else if (bt < 128) {    // peT[b][c][d][j] = pe[b,j,d,c]; d=3 zeroed
            int i2 = bt - 64; int b = i2 >> 4, t = i2 & 15, tj = t >> 2, d = t & 3;
            if (d == 3) {
                #pragma unroll
                for (int i = 0; i < 16; ++i) { int idx = i * 256 + tid; int c = idx >> 6, jl = idx & 63;
                    peT[((size_t)((b * 64 + c) * 4 + 3)) * 256 + tj * 64 + jl] = 0; }
            } else {
                #pragma unroll
                for (int i = 0; i < 16; ++i) { int idx = i * 256 + tid; int jl = idx >> 6, c = idx & 63;
                    sT[jl][c] = pe[((size_t)(b * 256 + tj * 64 + jl)) * 192 + d * 64 + c]; }
                __syncthreads();
                #pragma unroll
                for (int i = 0; i < 16; ++i) { int idx = i * 256 + tid; int c = idx >> 6, jl = idx & 63;
                    peT[((size_t)((b * 64 + c) * 4 + d)) * 256 + tj * 64 + jl] = f2bf(sT[jl][c]); }
            }
        } else if (bt < 144) {    // WoT[n][f] = inv_outW[f][n]
            int i2 = bt - 128; int tf = i2 >> 2, tn = i2 & 3;
            #pragma unroll
            for (int i = 0; i < 16; ++i) { int idx = i * 256 + tid; int fl = idx >> 6, nl = idx & 63;
                sT[fl][nl] = inv_outW[(size_t)(tf * 64 + fl) * 256 + tn * 64 + nl]; }
            __syncthreads();
            #pragma unroll
            for (int i = 0; i < 16; ++i) { int idx = i * 256 + tid; int nl = idx >> 6, fl = idx & 63;
                WoT[(size_t)(tn * 64 + nl) * 256 + tf * 64 + fl] = f2bf(sT[fl][nl]); }
        } else {                  // EoT[c'][c] = equi_outW[c][c']
            #pragma unroll
            for (int i = 0; i < 16; ++i) { int idx = i * 256 + tid; int cl = idx >> 6, c2i = idx & 63;
                sT[cl][c2i] = equi_outW[cl * 64 + c2i]; }
            __syncthreads();
            #pragma unroll
            for (int i = 0; i < 16; ++i) { int idx = i * 256 + tid; int c2i = idx >> 6, cl = idx & 63;
                EoT[c2i * 64 + cl] = f2bf(sT[cl][c2i]); }
        }
    }
}

// ---------------------------------------------------------------------------
// GEMM kernel: one block per (b,q,jc); 4 waves; ~34 KB LDS -> 4 blocks/CU
// (byte-identical to round 13)
// ---------------------------------------------------------------------------
constexpr int GA_AH   = 0;        // A: 64x128 bf16 (16K) / H: 64x256 (32K) / sPT 96x136B
constexpr int GA_EQ   = 32768;    // 192 f32
constexpr int GA_MASK = 33536;    // 64 f32
constexpr int GA_BYTES = 33792;

__launch_bounds__(256, 4)
__global__ void semla_gemm(const float* __restrict__ equis, const float* __restrict__ edges,
                           const int* __restrict__ adj, const float* __restrict__ mb2,
                           const short* __restrict__ W1T, const short* __restrict__ W2T,
                           const float* __restrict__ c1, const float* __restrict__ c2,
                           float* __restrict__ out, unsigned short* __restrict__ PT) {
    extern __shared__ char smem[];
    float* sEQ   = (float*)(smem + GA_EQ);
    float* sMask = (float*)(smem + GA_MASK);

    const int tid  = threadIdx.x;
    const int lane = tid & 63;
    const int w    = tid >> 6;
    const int bid  = blockIdx.x;
    const int xg   = bid & 7;
    const int tg   = bid >> 3;
    const int g    = xg + ((tg >> 8) << 3);
    const int b    = g >> 2;
    const int jc   = g & 3;
    const int bq   = (b << 8) + (tg & 255);

    const int lrow = lane & 15;
    const int kgrp = (lane >> 4) << 3;
    const int drow = (lane >> 4) << 2;

    if (tid < 192) sEQ[tid] = equis[(size_t)bq * 192 + tid];
    if (tid < 64)  sMask[tid] = adj[(size_t)bq * 256 + (jc << 6) + tid] ? 0.f : -1e30f;

    float c1v[4];
    #pragma unroll
    for (int ni = 0; ni < 4; ++ni)
        c1v[ni] = c1[bq * 256 + (w << 6) + (ni << 4) + lrow];
    const int ntiles = (w < 2) ? 3 : 2;
    const int nbase  = (w < 2) ? w * 48 : 96 + (w - 2) * 32;
    float b2v[3];
    #pragma unroll
    for (int ti = 0; ti < 3; ++ti)
        if (ti < ntiles) b2v[ti] = mb2[nbase + (ti << 4) + lrow];

    auto stA16 = [&](int row, int colbyte, short8 v) {   // A [64][128] bf16
        int byte = ((row << 8) + colbyte) ^ ((row & 7) << 4);
        *(short8*)(smem + GA_AH + byte) = v;
    };
    auto ldA = [&](int row, int kb) -> short8 {
        int byte = ((row << 8) + (kb << 1)) ^ ((row & 7) << 4);
        return *(const short8*)(smem + GA_AH + byte);
    };
    auto stH = [&](int row, int col, unsigned short v) { // H [64][256] bf16
        int byte = ((row << 9) + (col << 1)) ^ ((row & 7) << 4);
        *(unsigned short*)(smem + GA_AH + byte) = v;
    };
    auto ldH = [&](int row, int kb) -> short8 {
        int byte = ((row << 9) + (kb << 1)) ^ ((row & 7) << 4);
        return *(const short8*)(smem + GA_AH + byte);
    };

    __syncthreads();   // sEQ/sMask visible

    // ---- build A: cols 0..63 = dot(q,j), 64..127 = edges[b,q,j] (16B stores) ----
    {
        int r = tid >> 2, h = tid & 3;
        const float* erow = equis + (size_t)((b << 8) + (jc << 6) + r) * 192;
        #pragma unroll
        for (int g2 = 0; g2 < 2; ++g2) {
            int cg = h + g2 * 4;
            f32x4 lo = (f32x4)(0.f), hi = (f32x4)(0.f);
            #pragma unroll
            for (int d = 0; d < 3; ++d) {
                f32x4 e0 = *(const f32x4*)(erow + d * 64 + cg * 8);
                f32x4 e1 = *(const f32x4*)(erow + d * 64 + cg * 8 + 4);
                f32x4 q0 = *(const f32x4*)(sEQ + d * 64 + cg * 8);
                f32x4 q1 = *(const f32x4*)(sEQ + d * 64 + cg * 8 + 4);
                lo += e0 * q0; hi += e1 * q1;
            }
            stA16(r, cg * 16, pk8(lo, hi));
        }
        const float* ebase = edges + ((size_t)bq * 256 + (jc << 6)) * 64;
        #pragma unroll
        for (int g2 = 0; g2 < 2; ++g2) {
            int c8 = h + g2 * 4;
            f32x4 e0 = *(const f32x4*)(ebase + r * 64 + c8 * 8);
            f32x4 e1 = *(const f32x4*)(ebase + r * 64 + c8 * 8 + 4);
            stA16(r, 128 + c8 * 16, pk8(e0, e1));
        }
    }
    __syncthreads();

    // ---- GEMM1: H = silu(A @ W1[128:] + c1 + c2), K=128 ----
    f32x4 acc[4][4];
    #pragma unroll
    for (int mi = 0; mi < 4; ++mi)
        #pragma unroll
        for (int ni = 0; ni < 4; ++ni) acc[mi][ni] = (f32x4)(0.f);

    #pragma unroll
    for (int k0 = 0; k0 < 128; k0 += 32) {
        int kb = k0 + kgrp;
        short8 a0 = ldA(lrow, kb), a1 = ldA(16 + lrow, kb),
               a2 = ldA(32 + lrow, kb), a3 = ldA(48 + lrow, kb);
        short8 bf[4];
        #pragma unroll
        for (int ni = 0; ni < 4; ++ni)
            bf[ni] = *(const short8*)(W1T + ((w << 6) + (ni << 4) + lrow) * 128 + kb);
        #pragma unroll
        for (int ni = 0; ni < 4; ++ni) {
            acc[0][ni] = MFMA(a0, bf[ni], acc[0][ni]);
            acc[1][ni] = MFMA(a1, bf[ni], acc[1][ni]);
            acc[2][ni] = MFMA(a2, bf[ni], acc[2][ni]);
            acc[3][ni] = MFMA(a3, bf[ni], acc[3][ni]);
        }
    }
    __syncthreads();   // all waves done reading A (H aliases A)

    const float* c2base = c2 + ((size_t)((b << 8) + (jc << 6)) << 8);
    #pragma unroll
    for (int mi = 0; mi < 4; ++mi)
        #pragma unroll
        for (int r = 0; r < 4; ++r) {
            int row = (mi << 4) + drow + r;
            const float* c2row = c2base + (row << 8);
            #pragma unroll
            for (int ni = 0; ni < 4; ++ni) {
                int n = (w << 6) + (ni << 4) + lrow;
                float x = acc[mi][ni][r] + c1v[ni] + c2row[n];
                float hh = x * __builtin_amdgcn_rcpf(1.f + __expf(-x));
                stH(row, n, f2bfh(hh));
            }
        }
    __syncthreads();

    // ---- GEMM2: msgs = H @ W2 + b2 ; n-tiles 3/3/2/2 across waves ----
    f32x4 acc2[4][3];
    #pragma unroll
    for (int mi = 0; mi < 4; ++mi)
        #pragma unroll
        for (int ti = 0; ti < 3; ++ti) acc2[mi][ti] = (f32x4)(0.f);

    #pragma unroll
    for (int k0 = 0; k0 < 256; k0 += 32) {
        int kb = k0 + kgrp;
        short8 a0 = ldH(lrow, kb), a1 = ldH(16 + lrow, kb),
               a2 = ldH(32 + lrow, kb), a3 = ldH(48 + lrow, kb);
        short8 bt[3];
        #pragma unroll
        for (int ti = 0; ti < 3; ++ti)
            if (ti < ntiles) bt[ti] = *(const short8*)(W2T + (nbase + (ti << 4) + lrow) * 256 + kb);
        #pragma unroll
        for (int ti = 0; ti < 3; ++ti)
            if (ti < ntiles) {
                acc2[0][ti] = MFMA(a0, bt[ti], acc2[0][ti]);
                acc2[1][ti] = MFMA(a1, bt[ti], acc2[1][ti]);
                acc2[2][ti] = MFMA(a2, bt[ti], acc2[2][ti]);
                acc2[3][ti] = MFMA(a3, bt[ti], acc2[3][ti]);
            }
    }
    __syncthreads();   // H fully consumed; smem[0..13056) reused as sPT[96][136B]

    if (w < 2) {
        #pragma unroll
        for (int ti = 0; ti < 3; ++ti) {
            int n = nbase + (ti << 4) + lrow;
            float bias = b2v[ti];
            #pragma unroll
            for (int mi = 0; mi < 4; ++mi) {
                int j0 = (mi << 4) + drow;
                f32x4 mv = *(const f32x4*)(sMask + j0);
                unsigned lo = pk2(acc2[mi][ti][0] + bias + mv.x,
                                  acc2[mi][ti][1] + bias + mv.y);
                unsigned hi = pk2(acc2[mi][ti][2] + bias + mv.z,
                                  acc2[mi][ti][3] + bias + mv.w);
                *(unsigned*)(smem + n * 136 + j0 * 2)     = lo;
                *(unsigned*)(smem + n * 136 + j0 * 2 + 4) = hi;
            }
        }
    } else {
        #pragma unroll
        for (int mi = 0; mi < 4; ++mi)
            #pragma unroll
            for (int ti = 0; ti < 2; ++ti) {
                int n = nbase + (ti << 4) + lrow;
                #pragma unroll
                for (int r = 0; r < 4; ++r) {
                    int j = (jc << 6) + (mi << 4) + drow + r;
                    out[EDGE_OFF + ((size_t)bq * 256 + j) * 64 + (n - 96)] = acc2[mi][ti][r] + b2v[ti];
                }
            }
    }
    __syncthreads();

    // coalesced PT store: PT[bq*96+n][jc*64 .. +64] (64B per thread)
    if (tid < 192) {
        int n = tid >> 1, half = tid & 1;
        const char* src = smem + n * 136 + half * 64;
        unsigned short* dst = PT + (((size_t)bq * 96 + n) << 8) + (jc << 6) + half * 32;
        #pragma unroll
        for (int i = 0; i < 4; ++i)
            *(short8*)(dst + i * 8) = *(const short8*)(src + i * 16);
    }
}

// ---------------------------------------------------------------------------
// einsum kernel: one block per (b, c, qc); softmax in regs + 1 MFMA chain
// ---------------------------------------------------------------------------
constexpr int ES_A = 0;        // 64x256 bf16 swizzled = 32768
constexpr int ES_W = 32768;    // 64 f32
constexpr int ES_BYTES = 33024;

__launch_bounds__(256, 4)
__global__ void semla_einsum(const unsigned short* __restrict__ PT,
                             const unsigned short* __restrict__ hfT,
                             const unsigned short* __restrict__ peT,
                             unsigned short* __restrict__ OIb, unsigned short* __restrict__ OEb) {
    extern __shared__ char smem[];
    float* sW = (float*)(smem + ES_W);
    const int tid = threadIdx.x, lane = tid & 63, w = tid >> 6;
    const int bi = blockIdx.x;
    const int qc = bi & 3;
    const int t  = bi >> 2;
    const int b  = t / 96;
    const int c  = t - 96 * b;
    const int lrow = lane & 15, kgrp = (lane >> 4) << 3, drow = (lane >> 4) << 2;

    #pragma unroll
    for (int i = 0; i < 8; ++i) {
        int id = i * 256 + tid; int row = id >> 5, ck = id & 31;
        size_t src = (((size_t)((b << 8) + (qc << 6) + row) * 96 + c) << 8) + ck * 16;
        short8 v = *(const short8*)(PT + src);
        int byte = ((row << 9) + (ck << 4)) ^ ((row & 7) << 4);
        *(short8*)(smem + ES_A + byte) = v;
    }
    __syncthreads();

    {   // softmax: row r = tid>>2, 4 threads/row, 64 elems each, tree reductions
        int r = tid >> 2, p = tid & 3;
        float v[64];
        #pragma unroll
        for (int i = 0; i < 8; ++i) {
            int ck = p * 8 + i;
            int byte = ((r << 9) + (ck << 4)) ^ ((r & 7) << 4);
            short8 x = *(const short8*)(smem + ES_A + byte);
            #pragma unroll
            for (int e = 0; e < 8; ++e) v[i * 8 + e] = bf2f((unsigned short)x[e]);
        }
        // tree max (depth ~6 instead of 63-deep chain)
        float mt[8];
        #pragma unroll
        for (int i = 0; i < 8; ++i) {
            float a0 = fmaxf(v[i * 8 + 0], v[i * 8 + 1]);
            float a1 = fmaxf(v[i * 8 + 2], v[i * 8 + 3]);
            float a2 = fmaxf(v[i * 8 + 4], v[i * 8 + 5]);
            float a3 = fmaxf(v[i * 8 + 6], v[i * 8 + 7]);
            mt[i] = fmaxf(fmaxf(a0, a1), fmaxf(a2, a3));
        }
        float m = fmaxf(fmaxf(fmaxf(mt[0], mt[1]), fmaxf(mt[2], mt[3])),
                        fmaxf(fmaxf(mt[4], mt[5]), fmaxf(mt[6], mt[7])));
        m = fmaxf(m, __shfl_xor(m, 1)); m = fmaxf(m, __shfl_xor(m, 2));
        // 4-way partial sums (ILP)
        float s0 = 0.f, s1 = 0.f, s2 = 0.f, s3 = 0.f;
        float q0 = 0.f, q1 = 0.f, q2 = 0.f, q3 = 0.f;
        #pragma unroll
        for (int i = 0; i < 64; i += 4) {
            float e0 = __expf(v[i]     - m); v[i]     = e0;
            float e1 = __expf(v[i + 1] - m); v[i + 1] = e1;
            float e2 = __expf(v[i + 2] - m); v[i + 2] = e2;
            float e3 = __expf(v[i + 3] - m); v[i + 3] = e3;
            s0 += e0; s1 += e1; s2 += e2; s3 += e3;
            q0 = fmaf(e0, e0, q0); q1 = fmaf(e1, e1, q1);
            q2 = fmaf(e2, e2, q2); q3 = fmaf(e3, e3, q3);
        }
        float s = (s0 + s1) + (s2 + s3);
        float q = (q0 + q1) + (q2 + q3);
        s += __shfl_xor(s, 1); s += __shfl_xor(s, 2);
        q += __shfl_xor(q, 1); q += __shfl_xor(q, 2);
        float rs = (s > 0.f) ? 1.f / s : 0.f;
        if (p == 0) sW[r] = sqrtf(q) * rs;
        #pragma unroll
        for (int i = 0; i < 8; ++i) {
            int ck = p * 8 + i;
            short8 o;
            #pragma unroll
            for (int e = 0; e < 8; ++e) o[e] = (short)f2bfh(v[i * 8 + e] * rs);
            int byte = ((r << 9) + (ck << 4)) ^ ((r & 7) << 4);
            *(short8*)(smem + ES_A + byte) = o;
        }
    }
    __syncthreads();

    const unsigned short* Bbase =
        (c < 32) ? hfT + (((size_t)((b << 8) + (c << 3) + (lrow & 7))) << 8)
                 : peT + (((size_t)((((b << 6) + (c - 32)) << 2) + (lrow & 3))) << 8);
    f32x4 acc = (f32x4)(0.f);
    __builtin_amdgcn_s_setprio(1);
    #pragma unroll
    for (int k0 = 0; k0 < 256; k0 += 32) {
        int kb = k0 + kgrp;
        int byte = ((((w << 4) + lrow) << 9) + (kb << 1)) ^ ((lrow & 7) << 4);
        short8 a = *(const short8*)(smem + ES_A + byte);
        short8 bb = *(const short8*)(Bbase + kb);
        acc = MFMA(a, bb, acc);
    }
    __builtin_amdgcn_s_setprio(0);
    const int nvalid = (c < 32) ? 8 : 3;
    if (lrow < nvalid) {
        #pragma unroll
        for (int r2 = 0; r2 < 4; ++r2) {
            int ql = (w << 4) + drow + r2;
            float val = acc[r2] * sW[ql];
            size_t grow = (size_t)((b << 8) + (qc << 6) + ql);
            if (c < 32) OIb[(grow << 8) + (c << 3) + lrow] = f2bfh(val);
            else        OEb[(grow * 3 + lrow) * 64 + (c - 32)] = f2bfh(val);
        }
    }
}

// ---------------------------------------------------------------------------
// final projections (MFMA GEMMs)
// ---------------------------------------------------------------------------
constexpr int PJ_BYTES = 32768;

__launch_bounds__(256, 4)
__global__ void semla_proj(const unsigned short* __restrict__ OIb,
                           const unsigned short* __restrict__ OEb,
                           const unsigned short* __restrict__ WoT,
                           const unsigned short* __restrict__ EoT,
                           const float* __restrict__ inv_outb, float* __restrict__ out) {
    extern __shared__ char smem[];
    const int tid = threadIdx.x, lane = tid & 63, w = tid >> 6;
    const int lrow = lane & 15, kgrp = (lane >> 4) << 3, drow = (lane >> 4) << 2;
    const int bi = blockIdx.x;

    if (bi < 32) {
        const int mb = bi >> 1, nb = bi & 1;
        #pragma unroll
        for (int i = 0; i < 8; ++i) {
            int id = i * 256 + tid; int row = id >> 5, ck = id & 31;
            short8 v = *(const short8*)(OIb + (((size_t)(mb * 64 + row)) << 8) + ck * 16);
            int byte = ((row << 9) + (ck << 4)) ^ ((row & 7) << 4);
            *(short8*)(smem + byte) = v;
        }
        __syncthreads();
        f32x4 acc[4][2];
        #pragma unroll
        for (int mi = 0; mi < 4; ++mi)
            #pragma unroll
            for (int ti = 0; ti < 2; ++ti) acc[mi][ti] = (f32x4)(0.f);
        #pragma unroll
        for (int k0 = 0; k0 < 256; k0 += 32) {
            int kb = k0 + kgrp;
            short8 a[4];
            #pragma unroll
            for (int mi = 0; mi < 4; ++mi) {
                int byte = ((((mi << 4) + lrow) << 9) + (kb << 1)) ^ ((lrow & 7) << 4);
                a[mi] = *(const short8*)(smem + byte);
            }
            #pragma unroll
            for (int ti = 0; ti < 2; ++ti) {
                int n = nb * 128 + w * 32 + (ti << 4) + lrow;
                short8 bb = *(const short8*)(WoT + n * 256 + kb);
                #pragma unroll
                for (int mi = 0; mi < 4; ++mi) acc[mi][ti] = MFMA(a[mi], bb, acc[mi][ti]);
            }
        }
        #pragma unroll
        for (int ti = 0; ti < 2; ++ti) {
            int n = nb * 128 + w * 32 + (ti << 4) + lrow;
            float bias = inv_outb[n];
            #pragma unroll
            for (int mi = 0; mi < 4; ++mi)
                #pragma unroll
                for (int r = 0; r < 4; ++r) {
                    int row = mb * 64 + (mi << 4) + drow + r;
                    out[INV_OFF + (size_t)row * 256 + n] = acc[mi][ti][r] + bias;
                }
        }
    } else {
        const int mb = bi - 32;
        #pragma unroll
        for (int i = 0; i < 2; ++i) {
            int id = i * 256 + tid; int row = id >> 3, ck = id & 7;
            short8 v = *(const short8*)(OEb + (((size_t)(mb * 64 + row)) << 6) + ck * 16);
            int byte = ((row << 7) + (ck << 4)) ^ ((row & 7) << 4);
            *(short8*)(smem + byte) = v;
        }
        __syncthreads();
        f32x4 acc[4];
        #pragma unroll
        for (int ni = 0; ni < 4; ++ni) acc[ni] = (f32x4)(0.f);
        #pragma unroll
        for (int k0 = 0; k0 < 64; k0 += 32) {
            int kb = k0 + kgrp;
            int byte = ((((w << 4) + lrow) << 7) + (kb << 1)) ^ ((lrow & 7) << 4);
            short8 a = *(const short8*)(smem + byte);
            #pragma unroll
            for (int ni = 0; ni < 4; ++ni) {
                short8 bb = *(const short8*)(EoT + ((ni << 4) + lrow) * 64 + kb);
                acc[ni] = MFMA(a, bb, acc[ni]);
            }
        }
        #pragma unroll
        for (int ni = 0; ni < 4; ++ni)
            #pragma unroll
            for (int r = 0; r < 4; ++r) {
                int rowg = mb * 64 + (w << 4) + drow + r;
                int bq = rowg / 3, d = rowg - 3 * bq;
                out[EQUI_OFF + (size_t)bq * 192 + d * 64 + (ni << 4) + lrow] = acc[ni][r];
            }
    }
}

// ---------------------------------------------------------------------------
extern "C" void kernel_launch(void* const* d_in, const int* in_sizes, int n_in,
                              void* d_out, int out_size, void* d_ws, size_t ws_size,
                              hipStream_t stream) {
    const float* equis    = (const float*)d_in[0];
    const float* invs     = (const float*)d_in[1];
    const float* edges    = (const float*)d_in[2];
    const int*   adj      = (const int*)d_in[3];
    const float* qW       = (const float*)d_in[4];
    const float* qb       = (const float*)d_in[5];
    const float* kW       = (const float*)d_in[6];
    const float* kb       = (const float*)d_in[7];
    const float* mW1      = (const float*)d_in[8];
    const float* mb1      = (const float*)d_in[9];
    const float* mW2      = (const float*)d_in[10];
    const float* mb2      = (const float*)d_in[11];
    const float* inv_inW  = (const float*)d_in[12];
    const float* inv_inb  = (const float*)d_in[13];
    const float* inv_outW = (const float*)d_in[14];
    const float* inv_outb = (const float*)d_in[15];
    const float* equi_inW = (const float*)d_in[16];
    const float* equi_outW= (const float*)d_in[17];

    char* ws = (char*)d_ws;
    short* W1T = (short*)(ws + 0);                        //  64 KiB (256x128)
    short* W2T = (short*)(ws + 65536);                    //  80 KiB
    float* qm  = (float*)(ws + 147456);                   // 256 KiB
    float* km  = (float*)(ws + 409600);                   // 256 KiB
    float* hf  = (float*)(ws + 671744);                   //   1 MiB
    float* pe  = (float*)(ws + 1720320);                  // 768 KiB
    float* c1  = (float*)(ws + 2506752);                  //   1 MiB
    float* c2  = (float*)(ws + 3555328);                  //   1 MiB
    unsigned short* PT  = (unsigned short*)(ws + 4603904);   // 48 MiB
    unsigned short* peT = (unsigned short*)(ws + 54935552);  // 512 KiB
    unsigned short* hfT = (unsigned short*)(ws + 55459840);  // 512 KiB
    unsigned short* OIb = (unsigned short*)(ws + 55984128);  // 512 KiB
    unsigned short* OEb = (unsigned short*)(ws + 56508416);  // 384 KiB
    unsigned short* WoT = (unsigned short*)(ws + 56901632);  // 128 KiB
    unsigned short* EoT = (unsigned short*)(ws + 57032704);  //   8 KiB

    prep1<<<2336, 256, 0, stream>>>(invs, equis, qW, qb, kW, kb,
                                    inv_inW, inv_inb, equi_inW, mW1, mW2,
                                    qm, km, hf, pe, W1T, W2T);
    prep2<<<2193, 256, 0, stream>>>(qm, km, mW1, mb1, hf, pe, inv_outW, equi_outW,
                                    c1, c2, hfT, peT, WoT, EoT);
    semla_gemm<<<4096, 256, GA_BYTES, stream>>>(equis, edges, adj, mb2, W1T, W2T,
                                                c1, c2, (float*)d_out, PT);
    semla_einsum<<<1536, 256, ES_BYTES, stream>>>(PT, hfT, peT, OIb, OEb);
    semla_proj<<<80, 256, PJ_BYTES, stream>>>(OIb, OEb, WoT, EoT, inv_outb, (float*)d_out);
}